// Round 3
// baseline (7464.395 us; speedup 1.0000x reference)
//
#include <hip/hip_runtime.h>

#define BATCH 4
#define NPTS  2048
#define DIM   16
#define REGEPS 0.01f
#define DECAYF 0.9f
#define MINUPD 0.01f
#define MAXIT  50
#define LOGN   7.62461898616f   // ln(2048)
#define L2E    1.44269504089f   // log2(e)
#define LN2    0.69314718056f

// ---- workspace layout (units of 4 bytes) ----
#define OFF_SX    0
#define OFF_SQ    (BATCH*NPTS*DIM)            // 131072
#define OFF_F     (OFF_SQ + BATCH*NPTS)       // 139264
#define OFF_G     (OFF_F + BATCH*NPTS)        // 147456
#define OFF_MEAN  (OFF_G + BATCH*NPTS)        // 155648
#define OFF_SCALE (OFF_MEAN + BATCH*DIM)      // 155712
#define OFF_EPS0  (OFF_SCALE + BATCH)         // 155716
#define OFF_ARR   (OFF_EPS0 + BATCH)          // 155720 (4 ints, barrier arrive)
#define OFF_UPD2  (OFF_ARR + BATCH)           // 155724 (8 uints, dual-slot upd)
// end 155732 floats = 622928 B (round-1 used 623168 B OK)

// ============================================================
// Preprocess (as round 1, proven): mean/std/scale, sx, sq, extent->eps0,
// zero f/g, init arrive + upd slots.  grid = BATCH x 256
// ============================================================
__global__ __launch_bounds__(256) void ot_preproc(const float* __restrict__ state,
                                                  float* __restrict__ ws) {
  const int b = blockIdx.x;
  const int tid = threadIdx.x;
  __shared__ float s_sum[16][17];
  __shared__ float s_sq[16][17];
  __shared__ float s_mean[16];
  __shared__ float s_red[8];
  __shared__ float s_scale_sh;

  const float* st = state + b * NPTS * DIM;
  const int d = tid & 15, grp = tid >> 4;
  float sm = 0.f, s2 = 0.f;
  for (int n = grp; n < NPTS; n += 16) {
    float x = st[n * DIM + d];
    sm += x; s2 += x * x;
  }
  s_sum[grp][d] = sm; s_sq[grp][d] = s2;
  __syncthreads();
  if (tid < 16) {
    float S = 0.f, Q = 0.f;
    for (int g2 = 0; g2 < 16; ++g2) { S += s_sum[g2][tid]; Q += s_sq[g2][tid]; }
    float mean = S * (1.0f / NPTS);
    float var  = fmaxf(Q * (1.0f / NPTS) - mean * mean, 0.f);
    float sd   = sqrtf(var);
    s_mean[tid] = mean;
    ws[OFF_MEAN + b * DIM + tid] = mean;
    s_sum[0][tid] = sd;
  }
  __syncthreads();
  if (tid == 0) {
    float dm = 0.f;
    for (int d2 = 0; d2 < 16; ++d2) dm = fmaxf(dm, s_sum[0][d2]);
    if (dm == 0.f) dm = 1.f;
    float scale = dm * 4.0f;          // * sqrt(D=16)
    s_scale_sh = scale;
    ws[OFF_SCALE + b] = scale;
  }
  __syncthreads();

  const float inv_scale = 1.0f / s_scale_sh;
  float vmin = 3.0e38f, vmax = -3.0e38f;
  float* sx = ws + OFF_SX + b * NPTS * DIM;
  float* sq = ws + OFF_SQ + b * NPTS;
  for (int n = tid; n < NPTS; n += 256) {
    const float4* rp = (const float4*)(st + n * DIM);
    float4 xs0 = rp[0], xs1 = rp[1], xs2 = rp[2], xs3 = rp[3];
    float xv[16] = {xs0.x,xs0.y,xs0.z,xs0.w, xs1.x,xs1.y,xs1.z,xs1.w,
                    xs2.x,xs2.y,xs2.z,xs2.w, xs3.x,xs3.y,xs3.z,xs3.w};
    float ov[16];
    float q = 0.f;
    #pragma unroll
    for (int e = 0; e < 16; ++e) {
      float v = (xv[e] - s_mean[e]) * inv_scale;
      ov[e] = v; q += v * v;
      vmin = fminf(vmin, v); vmax = fmaxf(vmax, v);
    }
    float4* op = (float4*)(sx + n * DIM);
    op[0] = make_float4(ov[0],ov[1],ov[2],ov[3]);
    op[1] = make_float4(ov[4],ov[5],ov[6],ov[7]);
    op[2] = make_float4(ov[8],ov[9],ov[10],ov[11]);
    op[3] = make_float4(ov[12],ov[13],ov[14],ov[15]);
    sq[n] = q;
  }
  float* fv = ws + OFF_F + b * NPTS;
  float* gv = ws + OFF_G + b * NPTS;
  for (int n = tid; n < NPTS; n += 256) { fv[n] = 0.f; gv[n] = 0.f; }
  #pragma unroll
  for (int off = 32; off > 0; off >>= 1) {
    vmin = fminf(vmin, __shfl_xor(vmin, off));
    vmax = fmaxf(vmax, __shfl_xor(vmax, off));
  }
  const int wv = tid >> 6, ln = tid & 63;
  if (ln == 0) { s_red[wv] = vmin; s_red[4 + wv] = vmax; }
  __syncthreads();
  if (tid == 0) {
    float mn = fminf(fminf(s_red[0], s_red[1]), fminf(s_red[2], s_red[3]));
    float mx = fmaxf(fmaxf(s_red[4], s_red[5]), fmaxf(s_red[6], s_red[7]));
    ws[OFF_EPS0 + b] = mx - mn;
    ((unsigned int*)ws)[OFF_UPD2 + 2*b + 0] = 0u;
    ((unsigned int*)ws)[OFF_UPD2 + 2*b + 1] = 0u;
    ((int*)ws)[OFF_ARR + b] = 0;
  }
}

// ============================================================
// Persistent Sinkhorn kernel. 256 blocks x 512 threads, 1 block/CU.
// Per-batch (64-block) monotone arrive-counter barriers.
// LDS (dynamic 144KB): sxT[16][2048] + a2[2048] + wl2[2048].
// ============================================================
__device__ __forceinline__ void batch_barrier(int* arr, int target) {
  __syncthreads();   // compiler emits vmcnt(0) drain -> release stores done
  if (threadIdx.x == 0) {
    __hip_atomic_fetch_add(arr, 1, __ATOMIC_ACQ_REL, __HIP_MEMORY_SCOPE_AGENT);
    while (__hip_atomic_load(arr, __ATOMIC_ACQUIRE, __HIP_MEMORY_SCOPE_AGENT) < target)
      __builtin_amdgcn_s_sleep(8);
  }
  __syncthreads();
}

__device__ __forceinline__ void lse_sweep(const float* __restrict__ s_xt,
                                          const float* __restrict__ s_a2,
                                          const float (&sxs)[4][16],
                                          float (&M)[4], float (&S)[4], int l) {
  #pragma unroll
  for (int r = 0; r < 4; ++r) { M[r] = -3.0e38f; S[r] = 0.0f; }
  for (int c = 0; c < 8; ++c) {
    const int jb = c * 256 + 4 * l;
    const float4 av = *(const float4*)(s_a2 + jb);
    float acc[4][4];
    {
      const float4 xj = *(const float4*)(s_xt + jb);   // dd = 0
      #pragma unroll
      for (int r = 0; r < 4; ++r) {
        acc[r][0] = fmaf(sxs[r][0], xj.x, av.x);
        acc[r][1] = fmaf(sxs[r][0], xj.y, av.y);
        acc[r][2] = fmaf(sxs[r][0], xj.z, av.z);
        acc[r][3] = fmaf(sxs[r][0], xj.w, av.w);
      }
    }
    #pragma unroll
    for (int dd = 1; dd < 16; ++dd) {
      const float4 xj = *(const float4*)(s_xt + dd * 2048 + jb);
      #pragma unroll
      for (int r = 0; r < 4; ++r) {
        acc[r][0] = fmaf(sxs[r][dd], xj.x, acc[r][0]);
        acc[r][1] = fmaf(sxs[r][dd], xj.y, acc[r][1]);
        acc[r][2] = fmaf(sxs[r][dd], xj.z, acc[r][2]);
        acc[r][3] = fmaf(sxs[r][dd], xj.w, acc[r][3]);
      }
    }
    #pragma unroll
    for (int r = 0; r < 4; ++r) {
      const float cmx = fmaxf(fmaxf(acc[r][0], acc[r][1]), fmaxf(acc[r][2], acc[r][3]));
      const float nm = fmaxf(M[r], cmx);
      const float e0 = exp2f(M[r] - nm);
      const float sa = exp2f(acc[r][0]-nm) + exp2f(acc[r][1]-nm)
                     + exp2f(acc[r][2]-nm) + exp2f(acc[r][3]-nm);
      S[r] = fmaf(S[r], e0, sa);
      M[r] = nm;
    }
  }
}

__device__ __forceinline__ void lse_butterfly(float (&M)[4], float (&S)[4]) {
  #pragma unroll
  for (int off = 1; off < 64; off <<= 1) {
    #pragma unroll
    for (int r = 0; r < 4; ++r) {
      const float om = __shfl_xor(M[r], off);
      const float os = __shfl_xor(S[r], off);
      const float nm = fmaxf(M[r], om);
      S[r] = S[r] * exp2f(M[r] - nm) + os * exp2f(om - nm);
      M[r] = nm;
    }
  }
}

__global__ __launch_bounds__(512, 2) void ot_sinkhorn(float* __restrict__ ws,
                                                      const float* __restrict__ wlog) {
  extern __shared__ float lds[];
  float* s_xt  = lds;                 // [16][2048]
  float* s_a2  = lds + 16 * 2048;     // [2048]
  float* s_wl2 = s_a2 + 2048;         // [2048]

  const int bid = blockIdx.x;
  const int b  = bid >> 6;            // 64 blocks / batch
  const int rb = bid & 63;
  const int tid = threadIdx.x;
  const int w = tid >> 6, l = tid & 63;

  const float* __restrict__ sx = ws + OFF_SX + b * NPTS * DIM;
  const float* __restrict__ sq = ws + OFF_SQ + b * NPTS;
  float* fv = ws + OFF_F + b * NPTS;
  float* gv = ws + OFF_G + b * NPTS;
  const float* __restrict__ wl = wlog + b * NPTS;
  int* arr = (int*)ws + OFF_ARR + b;
  unsigned int* up2 = (unsigned int*)ws + OFF_UPD2 + 2 * b;

  // ---- one-time LDS staging: transposed sx + wl*log2e
  for (int j = tid; j < NPTS; j += 512) {
    const float4* rp = (const float4*)(sx + j * DIM);
    float4 t0 = rp[0], t1 = rp[1], t2 = rp[2], t3 = rp[3];
    s_xt[ 0*2048+j]=t0.x; s_xt[ 1*2048+j]=t0.y; s_xt[ 2*2048+j]=t0.z; s_xt[ 3*2048+j]=t0.w;
    s_xt[ 4*2048+j]=t1.x; s_xt[ 5*2048+j]=t1.y; s_xt[ 6*2048+j]=t1.z; s_xt[ 7*2048+j]=t1.w;
    s_xt[ 8*2048+j]=t2.x; s_xt[ 9*2048+j]=t2.y; s_xt[10*2048+j]=t2.z; s_xt[11*2048+j]=t2.w;
    s_xt[12*2048+j]=t3.x; s_xt[13*2048+j]=t3.y; s_xt[14*2048+j]=t3.z; s_xt[15*2048+j]=t3.w;
    s_wl2[j] = wl[j] * L2E;
  }
  // ---- own rows, prescaled by s2e = 2*log2e/eps (rescaled per iter)
  const int row0 = rb * 32 + w * 4;
  float sxs[4][16];
  #pragma unroll
  for (int r = 0; r < 4; ++r) {
    const float4* rp = (const float4*)(sx + (row0 + r) * DIM);
    float4 t0 = rp[0], t1 = rp[1], t2 = rp[2], t3 = rp[3];
    sxs[r][0]=t0.x;  sxs[r][1]=t0.y;  sxs[r][2]=t0.z;  sxs[r][3]=t0.w;
    sxs[r][4]=t1.x;  sxs[r][5]=t1.y;  sxs[r][6]=t1.z;  sxs[r][7]=t1.w;
    sxs[r][8]=t2.x;  sxs[r][9]=t2.y;  sxs[r][10]=t2.z; sxs[r][11]=t2.w;
    sxs[r][12]=t3.x; sxs[r][13]=t3.y; sxs[r][14]=t3.z; sxs[r][15]=t3.w;
  }
  float eps = ws[OFF_EPS0 + b];
  {
    const float s2e0 = 2.0f * L2E / eps;
    #pragma unroll
    for (int r = 0; r < 4; ++r)
      #pragma unroll
      for (int dd = 0; dd < 16; ++dd) sxs[r][dd] *= s2e0;
  }
  __syncthreads();

  int ph = 0;
  for (int it = 0; it < MAXIT; ++it) {
    const float le   = L2E / eps;
    const float eln2 = eps * LN2;

    // ================= F phase (src = g) =================
    {
      const int j4 = tid * 4;
      const float g0 = __hip_atomic_load(gv + j4 + 0, __ATOMIC_RELAXED, __HIP_MEMORY_SCOPE_AGENT);
      const float g1 = __hip_atomic_load(gv + j4 + 1, __ATOMIC_RELAXED, __HIP_MEMORY_SCOPE_AGENT);
      const float g2 = __hip_atomic_load(gv + j4 + 2, __ATOMIC_RELAXED, __HIP_MEMORY_SCOPE_AGENT);
      const float g3 = __hip_atomic_load(gv + j4 + 3, __ATOMIC_RELAXED, __HIP_MEMORY_SCOPE_AGENT);
      const float4 qj = *(const float4*)(sq + j4);
      *(float4*)(s_a2 + j4) = make_float4((g0 - qj.x) * le, (g1 - qj.y) * le,
                                          (g2 - qj.z) * le, (g3 - qj.w) * le);
    }
    __syncthreads();
    {
      float M[4], S[4];
      lse_sweep(s_xt, s_a2, sxs, M, S, l);
      lse_butterfly(M, S);
      if (l < 4) {
        const float Mr = (l==0)?M[0]:(l==1)?M[1]:(l==2)?M[2]:M[3];
        const float Sr = (l==0)?S[0]:(l==1)?S[1]:(l==2)?S[2]:S[3];
        const int i = row0 + l;
        const float qi = sq[i];
        const float fnew = fmaf(eps, LOGN, qi) - eln2 * (Mr + log2f(Sr));
        const float old = __hip_atomic_load(fv + i, __ATOMIC_RELAXED, __HIP_MEMORY_SCOPE_AGENT);
        __hip_atomic_store(fv + i, fnew, __ATOMIC_RELEASE, __HIP_MEMORY_SCOPE_AGENT);
        __hip_atomic_fetch_max(up2 + (it & 1), __float_as_uint(fabsf(fnew - old)),
                               __ATOMIC_RELAXED, __HIP_MEMORY_SCOPE_AGENT);
      }
    }
    ++ph; batch_barrier(arr, 64 * ph);

    // ================= G phase (src = f, + log_a) =================
    if (rb == 0 && tid == 0)
      __hip_atomic_store(up2 + ((it + 1) & 1), 0u, __ATOMIC_RELAXED, __HIP_MEMORY_SCOPE_AGENT);
    {
      const int j4 = tid * 4;
      const float f0 = __hip_atomic_load(fv + j4 + 0, __ATOMIC_RELAXED, __HIP_MEMORY_SCOPE_AGENT);
      const float f1 = __hip_atomic_load(fv + j4 + 1, __ATOMIC_RELAXED, __HIP_MEMORY_SCOPE_AGENT);
      const float f2 = __hip_atomic_load(fv + j4 + 2, __ATOMIC_RELAXED, __HIP_MEMORY_SCOPE_AGENT);
      const float f3 = __hip_atomic_load(fv + j4 + 3, __ATOMIC_RELAXED, __HIP_MEMORY_SCOPE_AGENT);
      const float4 qj = *(const float4*)(sq + j4);
      const float4 w2 = *(const float4*)(s_wl2 + j4);
      *(float4*)(s_a2 + j4) = make_float4(fmaf(f0 - qj.x, le, w2.x), fmaf(f1 - qj.y, le, w2.y),
                                          fmaf(f2 - qj.z, le, w2.z), fmaf(f3 - qj.w, le, w2.w));
    }
    __syncthreads();
    {
      float M[4], S[4];
      lse_sweep(s_xt, s_a2, sxs, M, S, l);
      lse_butterfly(M, S);
      if (l < 4) {
        const float Mr = (l==0)?M[0]:(l==1)?M[1]:(l==2)?M[2]:M[3];
        const float Sr = (l==0)?S[0]:(l==1)?S[1]:(l==2)?S[2]:S[3];
        const int i = row0 + l;
        const float qm = sq[i];
        const float gnew = qm - eln2 * (Mr + log2f(Sr));
        const float old = __hip_atomic_load(gv + i, __ATOMIC_RELAXED, __HIP_MEMORY_SCOPE_AGENT);
        __hip_atomic_store(gv + i, gnew, __ATOMIC_RELEASE, __HIP_MEMORY_SCOPE_AGENT);
        __hip_atomic_fetch_max(up2 + (it & 1), __float_as_uint(fabsf(gnew - old)),
                               __ATOMIC_RELAXED, __HIP_MEMORY_SCOPE_AGENT);
      }
    }
    if (it < MAXIT - 1) {
      ++ph; batch_barrier(arr, 64 * ph);
      const unsigned uu = __hip_atomic_load(up2 + (it & 1), __ATOMIC_RELAXED, __HIP_MEMORY_SCOPE_AGENT);
      const bool conv = (__uint_as_float(uu) < MINUPD) && (eps <= REGEPS);  // eps = pre-update (ref eps2)
      if (conv) break;
      const float en = fmaxf(eps * DECAYF, REGEPS);
      const float ratio = eps / en;          // sxs scale ∝ 1/eps
      eps = en;
      #pragma unroll
      for (int r = 0; r < 4; ++r)
        #pragma unroll
        for (int dd = 0; dd < 16; ++dd) sxs[r][dd] *= ratio;
    }
  }
}

// ============================================================
// Output (round-1, proven): new_state + uniform_log_w.
// grid = BATCH * (NPTS/8) = 1024 blocks x 256 threads.
// ============================================================
__global__ __launch_bounds__(256) void ot_out(float* __restrict__ ws,
                                              const float* __restrict__ wlog,
                                              float* __restrict__ out) {
  __shared__ float s_xt[DIM][256];
  __shared__ float s_p[256];
  __shared__ float s_q[256];
  const int bid = blockIdx.x;
  const int b  = bid >> 8;
  const int rb = bid & 255;
  const int tid = threadIdx.x;
  const int w = tid >> 6, l = tid & 63;
  const float invR = 1.0f / REGEPS;

  const float* __restrict__ sx = ws + OFF_SX + b * NPTS * DIM;
  const float* __restrict__ sq = ws + OFF_SQ + b * NPTS;
  const float* __restrict__ fv = ws + OFF_F + b * NPTS;
  const float* __restrict__ gv = ws + OFF_G + b * NPTS;
  const float* __restrict__ wl = wlog + b * NPTS;

  const int row0 = rb * 8 + w * 2;
  float sxm[2][DIM], cm2[2], qm[2], acc[2][DIM], accT[2];
  #pragma unroll
  for (int r = 0; r < 2; ++r) {
    const int mrow = row0 + r;
    cm2[r] = sq[mrow];
    qm[r]  = gv[mrow] * invR;
    const float4* rp = (const float4*)(sx + mrow * DIM);
    #pragma unroll
    for (int c4 = 0; c4 < 4; ++c4) {
      float4 t = rp[c4];
      sxm[r][c4*4+0] = -2.0f * t.x; sxm[r][c4*4+1] = -2.0f * t.y;
      sxm[r][c4*4+2] = -2.0f * t.z; sxm[r][c4*4+3] = -2.0f * t.w;
    }
    #pragma unroll
    for (int dd = 0; dd < DIM; ++dd) acc[r][dd] = 0.0f;
    accT[r] = 0.0f;
  }

  for (int k = 0; k < NPTS / 256; ++k) {
    __syncthreads();
    {
      const int n = k * 256 + tid;
      const float4* rp = (const float4*)(sx + n * DIM);
      float4 t0 = rp[0], t1 = rp[1], t2 = rp[2], t3 = rp[3];
      s_xt[0][tid]=t0.x;  s_xt[1][tid]=t0.y;  s_xt[2][tid]=t0.z;  s_xt[3][tid]=t0.w;
      s_xt[4][tid]=t1.x;  s_xt[5][tid]=t1.y;  s_xt[6][tid]=t1.z;  s_xt[7][tid]=t1.w;
      s_xt[8][tid]=t2.x;  s_xt[9][tid]=t2.y;  s_xt[10][tid]=t2.z; s_xt[11][tid]=t2.w;
      s_xt[12][tid]=t3.x; s_xt[13][tid]=t3.y; s_xt[14][tid]=t3.z; s_xt[15][tid]=t3.w;
      s_q[tid] = sq[n];
      s_p[tid] = wl[n] - LOGN + fv[n] * invR;
    }
    __syncthreads();
    const float4 pv = *(const float4*)&s_p[4 * l];
    const float4 qv = *(const float4*)&s_q[4 * l];
    float a2[2][4];
    #pragma unroll
    for (int r = 0; r < 2; ++r) {
      a2[r][0] = cm2[r] + qv.x; a2[r][1] = cm2[r] + qv.y;
      a2[r][2] = cm2[r] + qv.z; a2[r][3] = cm2[r] + qv.w;
    }
    #pragma unroll
    for (int dd = 0; dd < DIM; ++dd) {
      const float4 xj = *(const float4*)&s_xt[dd][4 * l];
      #pragma unroll
      for (int r = 0; r < 2; ++r) {
        const float xr = sxm[r][dd];
        a2[r][0] = fmaf(xr, xj.x, a2[r][0]);
        a2[r][1] = fmaf(xr, xj.y, a2[r][1]);
        a2[r][2] = fmaf(xr, xj.z, a2[r][2]);
        a2[r][3] = fmaf(xr, xj.w, a2[r][3]);
      }
    }
    float T[2][4];
    #pragma unroll
    for (int r = 0; r < 2; ++r) {
      T[r][0] = __expf(fmaf(fmaxf(a2[r][0], 0.f), -invR, pv.x + qm[r]));
      T[r][1] = __expf(fmaf(fmaxf(a2[r][1], 0.f), -invR, pv.y + qm[r]));
      T[r][2] = __expf(fmaf(fmaxf(a2[r][2], 0.f), -invR, pv.z + qm[r]));
      T[r][3] = __expf(fmaf(fmaxf(a2[r][3], 0.f), -invR, pv.w + qm[r]));
      accT[r] += (T[r][0] + T[r][1]) + (T[r][2] + T[r][3]);
    }
    #pragma unroll
    for (int dd = 0; dd < DIM; ++dd) {
      const float4 xj = *(const float4*)&s_xt[dd][4 * l];
      #pragma unroll
      for (int r = 0; r < 2; ++r) {
        float t = acc[r][dd];
        t = fmaf(T[r][0], xj.x, t);
        t = fmaf(T[r][1], xj.y, t);
        t = fmaf(T[r][2], xj.z, t);
        t = fmaf(T[r][3], xj.w, t);
        acc[r][dd] = t;
      }
    }
  }
  #pragma unroll
  for (int off = 1; off < 64; off <<= 1) {
    #pragma unroll
    for (int r = 0; r < 2; ++r) {
      #pragma unroll
      for (int dd = 0; dd < DIM; ++dd) acc[r][dd] += __shfl_xor(acc[r][dd], off);
      accT[r] += __shfl_xor(accT[r], off);
    }
  }
  if (l == 0) {
    const float scale = ws[OFF_SCALE + b];
    const float* mean = ws + OFF_MEAN + b * DIM;
    #pragma unroll
    for (int r = 0; r < 2; ++r) {
      const int mrow = row0 + r;
      float ov[16];
      #pragma unroll
      for (int dd = 0; dd < DIM; ++dd)
        ov[dd] = (float)NPTS * fmaf(scale, acc[r][dd], mean[dd] * accT[r]);
      float4* op = (float4*)(out + (b * NPTS + mrow) * DIM);
      op[0] = make_float4(ov[0],ov[1],ov[2],ov[3]);
      op[1] = make_float4(ov[4],ov[5],ov[6],ov[7]);
      op[2] = make_float4(ov[8],ov[9],ov[10],ov[11]);
      op[3] = make_float4(ov[12],ov[13],ov[14],ov[15]);
    }
  }
  if (tid < 8) out[BATCH * NPTS * DIM + b * NPTS + rb * 8 + tid] = -LOGN;
}

extern "C" void kernel_launch(void* const* d_in, const int* in_sizes, int n_in,
                              void* d_out, int out_size, void* d_ws, size_t ws_size,
                              hipStream_t stream) {
  (void)in_sizes; (void)n_in; (void)out_size; (void)ws_size;
  const float* state  = (const float*)d_in[0];
  const float* weight = (const float*)d_in[1];
  float* out = (float*)d_out;
  float* ws  = (float*)d_ws;

  ot_preproc<<<dim3(BATCH), dim3(256), 0, stream>>>(state, ws);

  const unsigned int dynLds = 147456;  // 144 KiB: sxT 128K + a2 8K + wl2 8K
  hipFuncSetAttribute((const void*)ot_sinkhorn,
                      hipFuncAttributeMaxDynamicSharedMemorySize, (int)dynLds);
  {
    float* wsf = ws;
    const float* wgt = weight;
    void* ka[2] = { (void*)&wsf, (void*)&wgt };
    if (hipLaunchCooperativeKernel((const void*)ot_sinkhorn, dim3(256), dim3(512),
                                   ka, dynLds, stream) != hipSuccess) {
      // fallback: plain launch (grid=256 <= #CUs, 1 block/CU resources -> co-resident)
      hipLaunchKernelGGL(ot_sinkhorn, dim3(256), dim3(512), dynLds, stream, ws, weight);
    }
  }

  ot_out<<<dim3(BATCH * NPTS / 8), dim3(256), 0, stream>>>(ws, weight, out);
}

// Round 4
// 3310.684 us; speedup vs baseline: 2.2546x; 2.2546x over previous
//
#include <hip/hip_runtime.h>

#define BATCH 4
#define NPTS  2048
#define DIM   16
#define REGEPS 0.01f
#define DECAYF 0.9f
#define MINUPD 0.01f
#define MAXIT  50
#define LOGN   7.62461898616f   // ln(2048)
#define L2E    1.44269504089f   // log2(e)
#define LN2    0.69314718056f

// ---- workspace layout (units of 4 bytes) ----
#define OFF_SX    0
#define OFF_SQ    (BATCH*NPTS*DIM)            // 131072
#define OFF_F     (OFF_SQ + BATCH*NPTS)       // 139264
#define OFF_G     (OFF_F + BATCH*NPTS)        // 147456
#define OFF_MEAN  (OFF_G + BATCH*NPTS)        // 155648
#define OFF_SCALE (OFF_MEAN + BATCH*DIM)      // 155712
#define OFF_EPS0  (OFF_SCALE + BATCH)         // 155716
// per-batch sync region: 64 floats (256B) each, 256B-aligned base.
//   +0  : arrive counter (int, RMW by 64 blocks)     } line 0
//   +2,3: upd dual slots (uint atomicMax)            } line 0
//   +32 : epoch flag (int, 1 writer, 63 pollers)     } line 1
#define OFF_SYNC  155776                      // 623104 B, 256B aligned
// end = 155776 + 4*64 = 156032 floats = 624128 B

// ============================================================
// Preprocess: mean/std/scale per batch, sx, sq, extent->eps0,
// zero f/g, init sync region.  grid = BATCH x 256
// ============================================================
__global__ __launch_bounds__(256) void ot_preproc(const float* __restrict__ state,
                                                  float* __restrict__ ws) {
  const int b = blockIdx.x;
  const int tid = threadIdx.x;
  __shared__ float s_sum[16][17];
  __shared__ float s_sq[16][17];
  __shared__ float s_mean[16];
  __shared__ float s_red[8];
  __shared__ float s_scale_sh;

  const float* st = state + b * NPTS * DIM;
  const int d = tid & 15, grp = tid >> 4;
  float sm = 0.f, s2 = 0.f;
  for (int n = grp; n < NPTS; n += 16) {
    float x = st[n * DIM + d];
    sm += x; s2 += x * x;
  }
  s_sum[grp][d] = sm; s_sq[grp][d] = s2;
  __syncthreads();
  if (tid < 16) {
    float S = 0.f, Q = 0.f;
    for (int g2 = 0; g2 < 16; ++g2) { S += s_sum[g2][tid]; Q += s_sq[g2][tid]; }
    float mean = S * (1.0f / NPTS);
    float var  = fmaxf(Q * (1.0f / NPTS) - mean * mean, 0.f);
    float sd   = sqrtf(var);
    s_mean[tid] = mean;
    ws[OFF_MEAN + b * DIM + tid] = mean;
    s_sum[0][tid] = sd;
  }
  __syncthreads();
  if (tid == 0) {
    float dm = 0.f;
    for (int d2 = 0; d2 < 16; ++d2) dm = fmaxf(dm, s_sum[0][d2]);
    if (dm == 0.f) dm = 1.f;
    float scale = dm * 4.0f;          // * sqrt(D=16)
    s_scale_sh = scale;
    ws[OFF_SCALE + b] = scale;
  }
  __syncthreads();

  const float inv_scale = 1.0f / s_scale_sh;
  float vmin = 3.0e38f, vmax = -3.0e38f;
  float* sx = ws + OFF_SX + b * NPTS * DIM;
  float* sq = ws + OFF_SQ + b * NPTS;
  for (int n = tid; n < NPTS; n += 256) {
    const float4* rp = (const float4*)(st + n * DIM);
    float4 xs0 = rp[0], xs1 = rp[1], xs2 = rp[2], xs3 = rp[3];
    float xv[16] = {xs0.x,xs0.y,xs0.z,xs0.w, xs1.x,xs1.y,xs1.z,xs1.w,
                    xs2.x,xs2.y,xs2.z,xs2.w, xs3.x,xs3.y,xs3.z,xs3.w};
    float ov[16];
    float q = 0.f;
    #pragma unroll
    for (int e = 0; e < 16; ++e) {
      float v = (xv[e] - s_mean[e]) * inv_scale;
      ov[e] = v; q += v * v;
      vmin = fminf(vmin, v); vmax = fmaxf(vmax, v);
    }
    float4* op = (float4*)(sx + n * DIM);
    op[0] = make_float4(ov[0],ov[1],ov[2],ov[3]);
    op[1] = make_float4(ov[4],ov[5],ov[6],ov[7]);
    op[2] = make_float4(ov[8],ov[9],ov[10],ov[11]);
    op[3] = make_float4(ov[12],ov[13],ov[14],ov[15]);
    sq[n] = q;
  }
  float* fv = ws + OFF_F + b * NPTS;
  float* gv = ws + OFF_G + b * NPTS;
  for (int n = tid; n < NPTS; n += 256) { fv[n] = 0.f; gv[n] = 0.f; }
  #pragma unroll
  for (int off = 32; off > 0; off >>= 1) {
    vmin = fminf(vmin, __shfl_xor(vmin, off));
    vmax = fmaxf(vmax, __shfl_xor(vmax, off));
  }
  const int wv = tid >> 6, ln = tid & 63;
  if (ln == 0) { s_red[wv] = vmin; s_red[4 + wv] = vmax; }
  __syncthreads();
  if (tid == 0) {
    float mn = fminf(fminf(s_red[0], s_red[1]), fminf(s_red[2], s_red[3]));
    float mx = fmaxf(fmaxf(s_red[4], s_red[5]), fmaxf(s_red[6], s_red[7]));
    ws[OFF_EPS0 + b] = mx - mn;
    int* sy = (int*)ws + OFF_SYNC + b * 64;
    sy[0] = 0;                       // arrive
    ((unsigned int*)sy)[2] = 0u;     // upd slot 0
    ((unsigned int*)sy)[3] = 0u;     // upd slot 1
    sy[32] = 0;                      // epoch
  }
}

// ============================================================
// Coherent (cross-XCD) 16B load: bypass L1/L2, read the coherent point.
// ============================================================
__device__ __forceinline__ float4 load_f4_coherent(const float* p) {
  float4 v;
  asm volatile("global_load_dwordx4 %0, %1, off sc0 sc1\n\t"
               "s_waitcnt vmcnt(0)"
               : "=v"(v) : "v"(p) : "memory");
  return v;
}

// ============================================================
// Epoch-broadcast barrier among the 64 blocks of one batch.
// arrive: RMW-only line.  epoch: 1 writer, 63 read-only pollers (RELAXED
// polls -> no per-poll cache invalidate; one ACQUIRE load on exit).
// ============================================================
__device__ __forceinline__ void batch_barrier(int* sy, int ph) {
  __syncthreads();
  if (threadIdx.x == 0) {
    int* arrive = sy;
    int* epoch  = sy + 32;
    const int old = __hip_atomic_fetch_add(arrive, 1, __ATOMIC_ACQ_REL,
                                           __HIP_MEMORY_SCOPE_AGENT);
    if (old == 64 * ph - 1) {
      __hip_atomic_store(epoch, ph, __ATOMIC_RELEASE, __HIP_MEMORY_SCOPE_AGENT);
    } else {
      while (__hip_atomic_load(epoch, __ATOMIC_RELAXED, __HIP_MEMORY_SCOPE_AGENT) < ph)
        __builtin_amdgcn_s_sleep(2);
      (void)__hip_atomic_load(epoch, __ATOMIC_ACQUIRE, __HIP_MEMORY_SCOPE_AGENT);
    }
  }
  __syncthreads();
}

__device__ __forceinline__ void lse_sweep(const float* __restrict__ s_xt,
                                          const float* __restrict__ s_a2,
                                          const float (&sxs)[4][16],
                                          float (&M)[4], float (&S)[4], int l) {
  #pragma unroll
  for (int r = 0; r < 4; ++r) { M[r] = -3.0e38f; S[r] = 0.0f; }
  for (int c = 0; c < 8; ++c) {
    const int jb = c * 256 + 4 * l;
    const float4 av = *(const float4*)(s_a2 + jb);
    float acc[4][4];
    {
      const float4 xj = *(const float4*)(s_xt + jb);   // dd = 0
      #pragma unroll
      for (int r = 0; r < 4; ++r) {
        acc[r][0] = fmaf(sxs[r][0], xj.x, av.x);
        acc[r][1] = fmaf(sxs[r][0], xj.y, av.y);
        acc[r][2] = fmaf(sxs[r][0], xj.z, av.z);
        acc[r][3] = fmaf(sxs[r][0], xj.w, av.w);
      }
    }
    #pragma unroll
    for (int dd = 1; dd < 16; ++dd) {
      const float4 xj = *(const float4*)(s_xt + dd * 2048 + jb);
      #pragma unroll
      for (int r = 0; r < 4; ++r) {
        acc[r][0] = fmaf(sxs[r][dd], xj.x, acc[r][0]);
        acc[r][1] = fmaf(sxs[r][dd], xj.y, acc[r][1]);
        acc[r][2] = fmaf(sxs[r][dd], xj.z, acc[r][2]);
        acc[r][3] = fmaf(sxs[r][dd], xj.w, acc[r][3]);
      }
    }
    #pragma unroll
    for (int r = 0; r < 4; ++r) {
      const float cmx = fmaxf(fmaxf(acc[r][0], acc[r][1]), fmaxf(acc[r][2], acc[r][3]));
      const float nm = fmaxf(M[r], cmx);
      const float e0 = exp2f(M[r] - nm);
      const float sa = exp2f(acc[r][0]-nm) + exp2f(acc[r][1]-nm)
                     + exp2f(acc[r][2]-nm) + exp2f(acc[r][3]-nm);
      S[r] = fmaf(S[r], e0, sa);
      M[r] = nm;
    }
  }
}

__device__ __forceinline__ void lse_butterfly(float (&M)[4], float (&S)[4]) {
  #pragma unroll
  for (int off = 1; off < 64; off <<= 1) {
    #pragma unroll
    for (int r = 0; r < 4; ++r) {
      const float om = __shfl_xor(M[r], off);
      const float os = __shfl_xor(S[r], off);
      const float nm = fmaxf(M[r], om);
      S[r] = S[r] * exp2f(M[r] - nm) + os * exp2f(om - nm);
      M[r] = nm;
    }
  }
}

// ============================================================
// Persistent Sinkhorn. 256 blocks x 512 threads, 1 block/CU (144KB LDS).
// ============================================================
__global__ __launch_bounds__(512, 2) void ot_sinkhorn(float* __restrict__ ws,
                                                      const float* __restrict__ wlog) {
  extern __shared__ float lds[];
  float* s_xt  = lds;                 // [16][2048]
  float* s_a2  = lds + 16 * 2048;     // [2048]
  float* s_wl2 = s_a2 + 2048;         // [2048]

  const int bid = blockIdx.x;
  const int b  = bid >> 6;            // 64 blocks / batch
  const int rb = bid & 63;
  const int tid = threadIdx.x;
  const int w = tid >> 6, l = tid & 63;

  const float* __restrict__ sx = ws + OFF_SX + b * NPTS * DIM;
  const float* __restrict__ sq = ws + OFF_SQ + b * NPTS;
  float* fv = ws + OFF_F + b * NPTS;
  float* gv = ws + OFF_G + b * NPTS;
  const float* __restrict__ wl = wlog + b * NPTS;
  int* sy = (int*)ws + OFF_SYNC + b * 64;
  unsigned int* up2 = (unsigned int*)sy + 2;

  // ---- one-time LDS staging: transposed sx + wl*log2e
  for (int j = tid; j < NPTS; j += 512) {
    const float4* rp = (const float4*)(sx + j * DIM);
    float4 t0 = rp[0], t1 = rp[1], t2 = rp[2], t3 = rp[3];
    s_xt[ 0*2048+j]=t0.x; s_xt[ 1*2048+j]=t0.y; s_xt[ 2*2048+j]=t0.z; s_xt[ 3*2048+j]=t0.w;
    s_xt[ 4*2048+j]=t1.x; s_xt[ 5*2048+j]=t1.y; s_xt[ 6*2048+j]=t1.z; s_xt[ 7*2048+j]=t1.w;
    s_xt[ 8*2048+j]=t2.x; s_xt[ 9*2048+j]=t2.y; s_xt[10*2048+j]=t2.z; s_xt[11*2048+j]=t2.w;
    s_xt[12*2048+j]=t3.x; s_xt[13*2048+j]=t3.y; s_xt[14*2048+j]=t3.z; s_xt[15*2048+j]=t3.w;
    s_wl2[j] = wl[j] * L2E;
  }
  // ---- own rows, prescaled by 2*log2e/eps (rescaled per iter)
  const int row0 = rb * 32 + w * 4;
  float sxs[4][16];
  #pragma unroll
  for (int r = 0; r < 4; ++r) {
    const float4* rp = (const float4*)(sx + (row0 + r) * DIM);
    float4 t0 = rp[0], t1 = rp[1], t2 = rp[2], t3 = rp[3];
    sxs[r][0]=t0.x;  sxs[r][1]=t0.y;  sxs[r][2]=t0.z;  sxs[r][3]=t0.w;
    sxs[r][4]=t1.x;  sxs[r][5]=t1.y;  sxs[r][6]=t1.z;  sxs[r][7]=t1.w;
    sxs[r][8]=t2.x;  sxs[r][9]=t2.y;  sxs[r][10]=t2.z; sxs[r][11]=t2.w;
    sxs[r][12]=t3.x; sxs[r][13]=t3.y; sxs[r][14]=t3.z; sxs[r][15]=t3.w;
  }
  float eps = ws[OFF_EPS0 + b];
  {
    const float s2e0 = 2.0f * L2E / eps;
    #pragma unroll
    for (int r = 0; r < 4; ++r)
      #pragma unroll
      for (int dd = 0; dd < 16; ++dd) sxs[r][dd] *= s2e0;
  }
  __syncthreads();

  int ph = 0;
  for (int it = 0; it < MAXIT; ++it) {
    const float le   = L2E / eps;
    const float eln2 = eps * LN2;

    // ================= F phase (src = g) =================
    {
      const int j4 = tid * 4;
      const float4 gj = load_f4_coherent(gv + j4);
      const float4 qj = *(const float4*)(sq + j4);
      *(float4*)(s_a2 + j4) = make_float4((gj.x - qj.x) * le, (gj.y - qj.y) * le,
                                          (gj.z - qj.z) * le, (gj.w - qj.w) * le);
    }
    __syncthreads();
    {
      float M[4], S[4];
      lse_sweep(s_xt, s_a2, sxs, M, S, l);
      lse_butterfly(M, S);
      if (l < 4) {
        const float Mr = (l==0)?M[0]:(l==1)?M[1]:(l==2)?M[2]:M[3];
        const float Sr = (l==0)?S[0]:(l==1)?S[1]:(l==2)?S[2]:S[3];
        const int i = row0 + l;
        const float qi = sq[i];
        const float fnew = fmaf(eps, LOGN, qi) - eln2 * (Mr + log2f(Sr));
        const float old = __hip_atomic_load(fv + i, __ATOMIC_RELAXED, __HIP_MEMORY_SCOPE_AGENT);
        __hip_atomic_store(fv + i, fnew, __ATOMIC_RELEASE, __HIP_MEMORY_SCOPE_AGENT);
        __hip_atomic_fetch_max(up2 + (it & 1), __float_as_uint(fabsf(fnew - old)),
                               __ATOMIC_RELAXED, __HIP_MEMORY_SCOPE_AGENT);
      }
    }
    ++ph; batch_barrier(sy, ph);

    // ================= G phase (src = f, + log_a) =================
    if (rb == 0 && tid == 0)
      __hip_atomic_store(up2 + ((it + 1) & 1), 0u, __ATOMIC_RELAXED, __HIP_MEMORY_SCOPE_AGENT);
    {
      const int j4 = tid * 4;
      const float4 fj = load_f4_coherent(fv + j4);
      const float4 qj = *(const float4*)(sq + j4);
      const float4 w2 = *(const float4*)(s_wl2 + j4);
      *(float4*)(s_a2 + j4) = make_float4(fmaf(fj.x - qj.x, le, w2.x), fmaf(fj.y - qj.y, le, w2.y),
                                          fmaf(fj.z - qj.z, le, w2.z), fmaf(fj.w - qj.w, le, w2.w));
    }
    __syncthreads();
    {
      float M[4], S[4];
      lse_sweep(s_xt, s_a2, sxs, M, S, l);
      lse_butterfly(M, S);
      if (l < 4) {
        const float Mr = (l==0)?M[0]:(l==1)?M[1]:(l==2)?M[2]:M[3];
        const float Sr = (l==0)?S[0]:(l==1)?S[1]:(l==2)?S[2]:S[3];
        const int i = row0 + l;
        const float qm = sq[i];
        const float gnew = qm - eln2 * (Mr + log2f(Sr));
        const float old = __hip_atomic_load(gv + i, __ATOMIC_RELAXED, __HIP_MEMORY_SCOPE_AGENT);
        __hip_atomic_store(gv + i, gnew, __ATOMIC_RELEASE, __HIP_MEMORY_SCOPE_AGENT);
        __hip_atomic_fetch_max(up2 + (it & 1), __float_as_uint(fabsf(gnew - old)),
                               __ATOMIC_RELAXED, __HIP_MEMORY_SCOPE_AGENT);
      }
    }
    if (it < MAXIT - 1) {
      ++ph; batch_barrier(sy, ph);
      const unsigned uu = __hip_atomic_load(up2 + (it & 1), __ATOMIC_RELAXED, __HIP_MEMORY_SCOPE_AGENT);
      const bool conv = (__uint_as_float(uu) < MINUPD) && (eps <= REGEPS);  // eps = pre-update (ref eps2)
      if (conv) break;
      const float en = fmaxf(eps * DECAYF, REGEPS);
      const float ratio = eps / en;          // sxs scale ∝ 1/eps
      eps = en;
      #pragma unroll
      for (int r = 0; r < 4; ++r)
        #pragma unroll
        for (int dd = 0; dd < 16; ++dd) sxs[r][dd] *= ratio;
    }
  }
}

// ============================================================
// Output (proven): new_state + uniform_log_w.
// grid = BATCH * (NPTS/8) = 1024 blocks x 256 threads.
// ============================================================
__global__ __launch_bounds__(256) void ot_out(float* __restrict__ ws,
                                              const float* __restrict__ wlog,
                                              float* __restrict__ out) {
  __shared__ float s_xt[DIM][256];
  __shared__ float s_p[256];
  __shared__ float s_q[256];
  const int bid = blockIdx.x;
  const int b  = bid >> 8;
  const int rb = bid & 255;
  const int tid = threadIdx.x;
  const int w = tid >> 6, l = tid & 63;
  const float invR = 1.0f / REGEPS;

  const float* __restrict__ sx = ws + OFF_SX + b * NPTS * DIM;
  const float* __restrict__ sq = ws + OFF_SQ + b * NPTS;
  const float* __restrict__ fv = ws + OFF_F + b * NPTS;
  const float* __restrict__ gv = ws + OFF_G + b * NPTS;
  const float* __restrict__ wl = wlog + b * NPTS;

  const int row0 = rb * 8 + w * 2;
  float sxm[2][DIM], cm2[2], qm[2], acc[2][DIM], accT[2];
  #pragma unroll
  for (int r = 0; r < 2; ++r) {
    const int mrow = row0 + r;
    cm2[r] = sq[mrow];
    qm[r]  = gv[mrow] * invR;
    const float4* rp = (const float4*)(sx + mrow * DIM);
    #pragma unroll
    for (int c4 = 0; c4 < 4; ++c4) {
      float4 t = rp[c4];
      sxm[r][c4*4+0] = -2.0f * t.x; sxm[r][c4*4+1] = -2.0f * t.y;
      sxm[r][c4*4+2] = -2.0f * t.z; sxm[r][c4*4+3] = -2.0f * t.w;
    }
    #pragma unroll
    for (int dd = 0; dd < DIM; ++dd) acc[r][dd] = 0.0f;
    accT[r] = 0.0f;
  }

  for (int k = 0; k < NPTS / 256; ++k) {
    __syncthreads();
    {
      const int n = k * 256 + tid;
      const float4* rp = (const float4*)(sx + n * DIM);
      float4 t0 = rp[0], t1 = rp[1], t2 = rp[2], t3 = rp[3];
      s_xt[0][tid]=t0.x;  s_xt[1][tid]=t0.y;  s_xt[2][tid]=t0.z;  s_xt[3][tid]=t0.w;
      s_xt[4][tid]=t1.x;  s_xt[5][tid]=t1.y;  s_xt[6][tid]=t1.z;  s_xt[7][tid]=t1.w;
      s_xt[8][tid]=t2.x;  s_xt[9][tid]=t2.y;  s_xt[10][tid]=t2.z; s_xt[11][tid]=t2.w;
      s_xt[12][tid]=t3.x; s_xt[13][tid]=t3.y; s_xt[14][tid]=t3.z; s_xt[15][tid]=t3.w;
      s_q[tid] = sq[n];
      s_p[tid] = wl[n] - LOGN + fv[n] * invR;
    }
    __syncthreads();
    const float4 pv = *(const float4*)&s_p[4 * l];
    const float4 qv = *(const float4*)&s_q[4 * l];
    float a2[2][4];
    #pragma unroll
    for (int r = 0; r < 2; ++r) {
      a2[r][0] = cm2[r] + qv.x; a2[r][1] = cm2[r] + qv.y;
      a2[r][2] = cm2[r] + qv.z; a2[r][3] = cm2[r] + qv.w;
    }
    #pragma unroll
    for (int dd = 0; dd < DIM; ++dd) {
      const float4 xj = *(const float4*)&s_xt[dd][4 * l];
      #pragma unroll
      for (int r = 0; r < 2; ++r) {
        const float xr = sxm[r][dd];
        a2[r][0] = fmaf(xr, xj.x, a2[r][0]);
        a2[r][1] = fmaf(xr, xj.y, a2[r][1]);
        a2[r][2] = fmaf(xr, xj.z, a2[r][2]);
        a2[r][3] = fmaf(xr, xj.w, a2[r][3]);
      }
    }
    float T[2][4];
    #pragma unroll
    for (int r = 0; r < 2; ++r) {
      T[r][0] = __expf(fmaf(fmaxf(a2[r][0], 0.f), -invR, pv.x + qm[r]));
      T[r][1] = __expf(fmaf(fmaxf(a2[r][1], 0.f), -invR, pv.y + qm[r]));
      T[r][2] = __expf(fmaf(fmaxf(a2[r][2], 0.f), -invR, pv.z + qm[r]));
      T[r][3] = __expf(fmaf(fmaxf(a2[r][3], 0.f), -invR, pv.w + qm[r]));
      accT[r] += (T[r][0] + T[r][1]) + (T[r][2] + T[r][3]);
    }
    #pragma unroll
    for (int dd = 0; dd < DIM; ++dd) {
      const float4 xj = *(const float4*)&s_xt[dd][4 * l];
      #pragma unroll
      for (int r = 0; r < 2; ++r) {
        float t = acc[r][dd];
        t = fmaf(T[r][0], xj.x, t);
        t = fmaf(T[r][1], xj.y, t);
        t = fmaf(T[r][2], xj.z, t);
        t = fmaf(T[r][3], xj.w, t);
        acc[r][dd] = t;
      }
    }
  }
  #pragma unroll
  for (int off = 1; off < 64; off <<= 1) {
    #pragma unroll
    for (int r = 0; r < 2; ++r) {
      #pragma unroll
      for (int dd = 0; dd < DIM; ++dd) acc[r][dd] += __shfl_xor(acc[r][dd], off);
      accT[r] += __shfl_xor(accT[r], off);
    }
  }
  if (l == 0) {
    const float scale = ws[OFF_SCALE + b];
    const float* mean = ws + OFF_MEAN + b * DIM;
    #pragma unroll
    for (int r = 0; r < 2; ++r) {
      const int mrow = row0 + r;
      float ov[16];
      #pragma unroll
      for (int dd = 0; dd < DIM; ++dd)
        ov[dd] = (float)NPTS * fmaf(scale, acc[r][dd], mean[dd] * accT[r]);
      float4* op = (float4*)(out + (b * NPTS + mrow) * DIM);
      op[0] = make_float4(ov[0],ov[1],ov[2],ov[3]);
      op[1] = make_float4(ov[4],ov[5],ov[6],ov[7]);
      op[2] = make_float4(ov[8],ov[9],ov[10],ov[11]);
      op[3] = make_float4(ov[12],ov[13],ov[14],ov[15]);
    }
  }
  if (tid < 8) out[BATCH * NPTS * DIM + b * NPTS + rb * 8 + tid] = -LOGN;
}

extern "C" void kernel_launch(void* const* d_in, const int* in_sizes, int n_in,
                              void* d_out, int out_size, void* d_ws, size_t ws_size,
                              hipStream_t stream) {
  (void)in_sizes; (void)n_in; (void)out_size; (void)ws_size;
  const float* state  = (const float*)d_in[0];
  const float* weight = (const float*)d_in[1];
  float* out = (float*)d_out;
  float* ws  = (float*)d_ws;

  ot_preproc<<<dim3(BATCH), dim3(256), 0, stream>>>(state, ws);

  const unsigned int dynLds = 147456;  // 144 KiB: sxT 128K + a2 8K + wl2 8K
  hipFuncSetAttribute((const void*)ot_sinkhorn,
                      hipFuncAttributeMaxDynamicSharedMemorySize, (int)dynLds);
  // plain launch: 256 blocks x 512 thr, 144KB LDS -> 1 block/CU, all co-resident
  hipLaunchKernelGGL(ot_sinkhorn, dim3(256), dim3(512), dynLds, stream, ws, weight);

  ot_out<<<dim3(BATCH * NPTS / 8), dim3(256), 0, stream>>>(ws, weight, out);
}